// Round 2
// baseline (10108.373 us; speedup 1.0000x reference)
//
#include <hip/hip_runtime.h>
#include <hip/hip_bf16.h>

typedef __hip_bfloat16 bf16;
typedef float f4 __attribute__((ext_vector_type(4)));   // native vec for nontemporal builtins

#define SLOPE 0.2f

__device__ __forceinline__ float lrelu(float v) { return v > 0.f ? v : SLOPE * v; }
__device__ __forceinline__ bf16 f2b(float v) { return __float2bfloat16(v); }
// exact bf16 -> f32 conversions from a packed dword (low / high halves)
__device__ __forceinline__ float blo(unsigned u) { return __uint_as_float(u << 16); }
__device__ __forceinline__ float bhi(unsigned u) { return __uint_as_float(u & 0xffff0000u); }

// ---------------------------------------------------------------------------
// Kernel 0: weight-norm for the dilated conv, TRANSPOSED output:
//   wnt[(i*3+k)*128 + c] = g[c] * v[c][i][k] / ||v[c]||_F
// Transposed layout makes dconv's weight staging a contiguous stream.
// ---------------------------------------------------------------------------
__global__ void wnorm_kernel(const float* __restrict__ v, const float* __restrict__ g,
                             float* __restrict__ wnt) {
    int c = blockIdx.x;      // 128 blocks
    int t = threadIdx.x;     // 128 threads
    __shared__ float red[128];
    float s = 0.f;
    for (int e = t; e < 384; e += 128) {
        float x = v[c * 384 + e];
        s += x * x;
    }
    red[t] = s;
    __syncthreads();
    for (int off = 64; off > 0; off >>= 1) {
        if (t < off) red[t] += red[t + off];
        __syncthreads();
    }
    float scale = g[c] / sqrtf(red[0]);
    for (int e = t; e < 384; e += 128) {
        wnt[e * 128 + c] = scale * v[c * 384 + e];
    }
}

// ---------------------------------------------------------------------------
// Kernel 1: location-variable conv + bias + leaky-relu -> h (bf16)
//
// Block = (b, l-group of 16, o-quad). Weight loads are float4 ALONG l
// (the innermost, contiguous dim) -> every 64B line fully consumed, weights
// fetched exactly once, perfectly coalesced. x is read straight through
// L1/L2 (32 sibling o-quad blocks share the same 1MB x slab; the swizzle
// pins all 32 siblings to one XCD so its L2 serves them).
// LDS = double-buffered 6KB weight chunk only -> 4 blocks/CU (16 waves).
// Thread owns 4 o x 8 consecutive s within one l: acc[4][8].
// ---------------------------------------------------------------------------
#define ICH 8   // i-channels per chunk, 16 chunks

__global__ void __launch_bounds__(256, 4)
lvc_kernel(const float* __restrict__ x, const float* __restrict__ w,
           const float* __restrict__ bias, bf16* __restrict__ h) {
    __shared__ float wls[2][ICH * 4 * 3 * 16];   // 2 x 6KB, [ii][o][k][ll]

    // decode with XCD grouping: all 32 o-quads of one (b,lg) group land on
    // the same XCD (round-robin dispatch = blockIdx % 8), consecutive in time.
    int p   = blockIdx.x;
    int xcd = p & 7, j = p >> 3;
    int g   = xcd * 16 + (j >> 5);   // 0..127 = (b,lg) group
    int oq  = j & 31;                // o-quad
    int b = g >> 4, lg = g & 15;
    int tid = threadIdx.x;
    int l_loc = tid & 15, sq = tid >> 4;
    int s0 = sq * 8;
    int o0 = oq * 4;
    int tbase = lg * 2048;
    int l = lg * 16 + l_loc;

    // thread's x window: x[b, i, tbase + l_loc*128 + s0 - 1 + (0..9)]
    const float* xbase_t = x + (size_t)b * 128 * 32768 + (tbase + l_loc * 128 + s0 - 1);
    bool guardL = (lg == 0) && (tid == 0);     // only thread reading x[-1]
    bool guardR = (lg == 15) && (tid == 255);  // only thread reading x[32768]

    f4 wpre0, wpre1;

    // weight chunk: 384 float4 units; unit e4 -> (ii,o,k, 4 l's), src float4
    // is 16B contiguous along l. nontemporal: weights are single-use stream.
#define LVC_LOADW(icn) do {                                                          \
        { int e4 = tid; int ll4 = e4 & 3; int r = e4 >> 2;                           \
          int kk = r % 3; int oo = (r / 3) & 3; int ii2 = r / 12;                    \
          wpre0 = __builtin_nontemporal_load((const f4*)&w[                          \
              ((((size_t)(b * 128 + (icn) * ICH + ii2)) * 128 + o0 + oo) * 3 + kk) * 256 \
              + lg * 16 + ll4 * 4]); }                                               \
        if (tid < 128) {                                                             \
          int e4 = tid + 256; int ll4 = e4 & 3; int r = e4 >> 2;                     \
          int kk = r % 3; int oo = (r / 3) & 3; int ii2 = r / 12;                    \
          wpre1 = __builtin_nontemporal_load((const f4*)&w[                          \
              ((((size_t)(b * 128 + (icn) * ICH + ii2)) * 128 + o0 + oo) * 3 + kk) * 256 \
              + lg * 16 + ll4 * 4]); }                                               \
    } while (0)

#define LVC_WRITEW(nb) do {                                                          \
        *(f4*)&wls[nb][tid * 4] = wpre0;                                             \
        if (tid < 128) *(f4*)&wls[nb][(tid + 256) * 4] = wpre1;                      \
    } while (0)

    float acc[4][8];
#pragma unroll
    for (int o = 0; o < 4; o++)
#pragma unroll
        for (int u = 0; u < 8; u++) acc[o][u] = 0.f;

    LVC_LOADW(0);
    LVC_WRITEW(0);
    __syncthreads();

    for (int ic = 0; ic < 16; ic++) {
        int cur = ic & 1;
        if (ic < 15) LVC_LOADW(ic + 1);      // prefetch next chunk into regs
        const float* wp = wls[cur];
#pragma unroll
        for (int ii = 0; ii < ICH; ii++) {
            const float* xrow = xbase_t + (size_t)(ic * ICH + ii) * 32768;
            float xw0 = 0.f, xw9 = 0.f;
            if (!guardL) xw0 = xrow[0];
            if (!guardR) xw9 = xrow[9];
            f4 xa = *(const f4*)(xrow + 1);   // aligned (offset % 4 == 0)
            f4 xb = *(const f4*)(xrow + 5);
            float xw[10] = {xw0, xa.x, xa.y, xa.z, xa.w, xb.x, xb.y, xb.z, xb.w, xw9};
#pragma unroll
            for (int o = 0; o < 4; o++) {
                // 16-lane broadcast LDS reads (lanes differ only in l_loc)
                float w0 = wp[((ii * 4 + o) * 3 + 0) * 16 + l_loc];
                float w1 = wp[((ii * 4 + o) * 3 + 1) * 16 + l_loc];
                float w2 = wp[((ii * 4 + o) * 3 + 2) * 16 + l_loc];
#pragma unroll
                for (int u = 0; u < 8; u++)
                    acc[o][u] += w0 * xw[u] + w1 * xw[u + 1] + w2 * xw[u + 2];
            }
        }
        if (ic < 15) LVC_WRITEW(cur ^ 1);    // ds_write after compute (T14 split)
        __syncthreads();                     // one barrier per chunk
    }

    // epilogue: + bias[b,o,l], leaky-relu, bf16 store (2x ushort4 per o)
#pragma unroll
    for (int o = 0; o < 4; o++) {
        float bs = bias[((size_t)(b * 128 + o0 + o)) * 256 + l];
        union { bf16 bv[8]; ushort4 v4[2]; } pk;
#pragma unroll
        for (int u = 0; u < 8; u++) pk.bv[u] = f2b(lrelu(acc[o][u] + bs));
        bf16* hp = h + ((size_t)(b * 128 + o0 + o)) * 32768 + tbase + l_loc * 128 + s0;
        *(ushort4*)&hp[0] = pk.v4[0];
        *(ushort4*)&hp[4] = pk.v4[1];
    }
}

// ---------------------------------------------------------------------------
// Kernel 2: dilated (K=3, dilation 3) conv + conv_b + leaky-relu -> out
// h tile kept as bf16 in LDS (34KB, converted by shift on read) and weight
// chunks staged contiguously from transposed wnt (double-buffered 2x6KB)
// -> 47KB LDS -> 3 blocks/CU, one barrier per chunk.
// Layout: ht col = (t - tb) + 4 (interior 8B-aligned), halos at 1..3 / 132..134.
// ---------------------------------------------------------------------------
#define DICH 4   // i-channels per chunk, 32 chunks

__global__ void __launch_bounds__(256, 3)
dconv_kernel(const bf16* __restrict__ hws, const float* __restrict__ wnt,
             const float* __restrict__ cb, float* __restrict__ out) {
    __shared__ ushort ht[128][136];              // 34816 B, bf16 bits
    __shared__ float wls[2][DICH * 3 * 128];     // 2 x 6KB, [ii][k][c]

    int bid = blockIdx.x;
    int b = bid >> 8;
    int tb = (bid & 255) * 128;
    int tid = threadIdx.x;
    int sg = tid & 31, cg = tid >> 5;
    int s0 = sg * 4, c0 = cg * 16;

    // ---- stage h tile (bf16, once): interior as ushort4, halos scalar
    const ushort* hbase = (const ushort*)hws + (size_t)b * 128 * 32768;
#pragma unroll
    for (int q = 0; q < 16; q++) {
        int e = tid + 256 * q;                   // 0..4095
        int i = e >> 5, m = e & 31;
        ushort4 val = *(const ushort4*)&hbase[(size_t)i * 32768 + tb + 4 * m];
        *(ushort4*)&ht[i][4 + 4 * m] = val;
    }
    if (tid < 128) {
        const ushort* hrow = hbase + (size_t)tid * 32768;
#pragma unroll
        for (int d = 0; d < 3; d++) {
            int gl = tb - 3 + d;
            ht[tid][1 + d] = (gl >= 0) ? hrow[gl] : (ushort)0;
            int gr = tb + 128 + d;
            ht[tid][132 + d] = (gr < 32768) ? hrow[gr] : (ushort)0;
        }
    }

    f4 wq0, wq1;
#define DC_LOADW(icn) do {                                                   \
        wq0 = *(const f4*)&wnt[(icn) * 1536 + tid * 4];                      \
        if (tid < 128) wq1 = *(const f4*)&wnt[(icn) * 1536 + (tid + 256) * 4]; \
    } while (0)
#define DC_WRITEW(nb) do {                                                   \
        *(f4*)&wls[nb][tid * 4] = wq0;                                       \
        if (tid < 128) *(f4*)&wls[nb][(tid + 256) * 4] = wq1;                \
    } while (0)

    DC_LOADW(0);
    DC_WRITEW(0);

    float acc[4][16];
#pragma unroll
    for (int u = 0; u < 4; u++)
#pragma unroll
        for (int n = 0; n < 16; n++) acc[u][n] = 0.f;

    __syncthreads();

    for (int ic = 0; ic < 32; ic++) {
        int cur = ic & 1;
        if (ic < 31) DC_LOADW(ic + 1);
#pragma unroll
        for (int ii = 0; ii < DICH; ii++) {
            int i = ic * DICH + ii;
            // aligned 8B reads covering cols s0..s0+11; taps use s0+1..s0+10
            uint2 q0 = *(const uint2*)&ht[i][s0];
            uint2 q1 = *(const uint2*)&ht[i][s0 + 4];
            uint2 q2 = *(const uint2*)&ht[i][s0 + 8];
            float xf[11];
            xf[0] = 0.f;
            xf[1] = bhi(q0.x); xf[2] = blo(q0.y); xf[3] = bhi(q0.y);
            xf[4] = blo(q1.x); xf[5] = bhi(q1.x); xf[6] = blo(q1.y); xf[7] = bhi(q1.y);
            xf[8] = blo(q2.x); xf[9] = bhi(q2.x); xf[10] = blo(q2.y);
            const float* wp = &wls[cur][ii * 3 * 128 + c0];
#pragma unroll
            for (int o4 = 0; o4 < 4; o4++) {
                float4 w0 = *(const float4*)&wp[0 * 128 + o4 * 4];
                float4 w1 = *(const float4*)&wp[1 * 128 + o4 * 4];
                float4 w2 = *(const float4*)&wp[2 * 128 + o4 * 4];
#pragma unroll
                for (int u = 0; u < 4; u++) {
                    float xa = xf[u + 1], xb = xf[u + 4], xc = xf[u + 7];
                    acc[u][o4 * 4 + 0] += w0.x * xa + w1.x * xb + w2.x * xc;
                    acc[u][o4 * 4 + 1] += w0.y * xa + w1.y * xb + w2.y * xc;
                    acc[u][o4 * 4 + 2] += w0.z * xa + w1.z * xb + w2.z * xc;
                    acc[u][o4 * 4 + 3] += w0.w * xa + w1.w * xb + w2.w * xc;
                }
            }
        }
        if (ic < 31) DC_WRITEW(cur ^ 1);
        __syncthreads();
    }

    // ---- epilogue: + conv_b[c], leaky-relu, fp32 float4 store
#pragma unroll
    for (int n = 0; n < 16; n++) {
        int c = c0 + n;
        float bc = cb[c];
        float4 pk;
        pk.x = lrelu(acc[0][n] + bc);
        pk.y = lrelu(acc[1][n] + bc);
        pk.z = lrelu(acc[2][n] + bc);
        pk.w = lrelu(acc[3][n] + bc);
        *(float4*)&out[((size_t)(b * 128 + c)) * 32768 + tb + s0] = pk;
    }
}

// ---------------------------------------------------------------------------
extern "C" void kernel_launch(void* const* d_in, const int* in_sizes, int n_in,
                              void* d_out, int out_size, void* d_ws, size_t ws_size,
                              hipStream_t stream) {
    const float* x      = (const float*)d_in[0];
    const float* weight = (const float*)d_in[1];
    const float* bias   = (const float*)d_in[2];
    const float* conv_v = (const float*)d_in[3];
    const float* conv_g = (const float*)d_in[4];
    const float* conv_b = (const float*)d_in[5];
    float* out = (float*)d_out;

    // workspace layout: [0, 192KiB) wnt (transposed, fp32) ;
    //                   [256KiB, 256KiB+64MiB) h (bf16)
    float* wnt = (float*)d_ws;
    bf16* h = (bf16*)((char*)d_ws + (size_t)262144);

    wnorm_kernel<<<dim3(128), dim3(128), 0, stream>>>(conv_v, conv_g, wnt);
    lvc_kernel<<<dim3(4096), dim3(256), 0, stream>>>(x, weight, bias, h);
    dconv_kernel<<<dim3(2048), dim3(256), 0, stream>>>(h, wnt, conv_b, out);
}